// Round 24
// baseline (31.755 us; speedup 1.0000x reference)
//
#include <hip/hip_runtime.h>

// MLP 30->24->19->14->10->6->2->1 via MFMA (v_mfma_f32_32x32x16_f16).
// R24 vs R23 (31.3-31.6us): PREFETCH DEPTH 2. Each wave keeps TWO tiles'
// loads in flight (8 dwordx4) in ping-pong register sets A/B; the loop is
// unrolled x2 with NAMED register sets (no runtime-indexed arrays). The
// compiler's counted vmcnt before consuming set A leaves set B in flight.
// R22/R23 model: chain (~600cyc) < HBM latency (~900cyc) with only 1-tile
// depth -> per-tile stall; depth 2 covers it.
// Layouts (numerically verified R19-R23, absmax 1.95e-3):
//  C/D: col=lane&31, row=(reg&3)+8*(reg>>2)+4*(lane>>5).
//  A/B: lane holds elem[m_or_n=lane&31][k=16*ks+8*(lane>>5)+j].
//  Bias folded as extra K-slot (W_eff[m][FIN]=bias, act k=FIN = 1.0).

#define NTHREADS 256
#define TPW 8                  // tiles (32 rows) per wave; even (unroll x2)

typedef __fp16       h2     __attribute__((ext_vector_type(2)));
typedef __fp16       half8  __attribute__((ext_vector_type(8)));
typedef float        f32x16 __attribute__((ext_vector_type(16)));
typedef unsigned int uint4v __attribute__((ext_vector_type(4)));

__device__ __forceinline__ h2 cpk(float a, float b) {
    return __builtin_bit_cast(h2, __builtin_amdgcn_cvt_pkrtz(a, b));
}
__device__ __forceinline__ h2 relu2(h2 v) {
    h2 z = {(__fp16)0.f, (__fp16)0.f};
#if __has_builtin(__builtin_elementwise_max)
    return __builtin_elementwise_max(v, z);
#else
    v.x = v.x > (__fp16)0.f ? v.x : (__fp16)0.f;
    v.y = v.y > (__fp16)0.f ? v.y : (__fp16)0.f;
    return v;
#endif
}
__device__ __forceinline__ unsigned ucast(h2 v) { return __builtin_bit_cast(unsigned, v); }

__device__ __forceinline__ f32x16 mfma_(half8 A, half8 B, f32x16 C) {
    return __builtin_amdgcn_mfma_f32_32x32x16_f16(A, B, C, 0, 0, 0);
}

// unaligned-tolerant float4 load (rows alternate 16B/8B alignment)
__device__ __forceinline__ float4 ldg4(const float* p) {
    float4 v;
    __builtin_memcpy(&v, p, 16);
    return v;
}

// ---- weight staging: W_eff[m][k] f16, m padded to 32, k padded to KPAD ----
template <int FIN, int FOUT, int KPAD>
__device__ __forceinline__ void stageW(const float* __restrict__ W, const float* __restrict__ B,
                                       __fp16* __restrict__ sbase, int t) {
    for (int idx = t; idx < 32 * KPAD; idx += NTHREADS) {
        int m = idx / KPAD;
        int k = idx & (KPAD - 1);
        float v = 0.f;
        if (m < FOUT) {
            if (k < FIN) v = W[m * FIN + k];
            else if (k == FIN) v = B[m];
        }
        int byte = idx * 2;
        byte ^= (m & 7) << 4;
        *(__fp16*)((char*)sbase + byte) = (__fp16)v;
    }
}

// A-fragment read: lane holds W_eff[m=lane&31][k = ks*16 + 8*(lane>>5) + j]
__device__ __forceinline__ half8 ldA(const __fp16* base, int KPAD, int ks, int lane) {
    int m = lane & 31;
    int byte = (m * KPAD + ks * 16 + ((lane >> 5) & 1) * 8) * 2;
    byte ^= (m & 7) << 4;
    return __builtin_bit_cast(half8, *(const uint4v*)((const char*)base + byte));
}

// B-fragment from accumulator D, k-block regs R (0 or 8); POS = bias slot.
template <int R, int POS>
__device__ __forceinline__ half8 bfrag(const f32x16& d, int lane) {
    unsigned u0 = ucast(relu2(cpk(d[R + 0], d[R + 1])));
    unsigned u1 = ucast(relu2(cpk(d[R + 2], d[R + 3])));
    unsigned u2 = ucast(relu2(cpk(d[R + 4], d[R + 5])));
    unsigned u3 = ucast(relu2(cpk(d[R + 6], d[R + 7])));
    bool lo = (lane & 32) == 0;
    unsigned s0 = __shfl_xor(u0, 32), s1 = __shfl_xor(u1, 32);
    unsigned s2 = __shfl_xor(u2, 32), s3 = __shfl_xor(u3, 32);
    unsigned w0 = lo ? u0 : s2;
    unsigned w1 = lo ? u1 : s3;
    unsigned w2 = lo ? s0 : u2;
    unsigned w3 = lo ? s1 : u3;
    if constexpr (POS >= 0) {
        constexpr bool hiT = POS >= 8;
        constexpr int  p   = POS & 7;
        constexpr unsigned bits = (p & 1) ? 0x3C000000u : 0x00003C00u;  // f16 1.0
        bool sel = (((lane & 32) != 0) == hiT);
        unsigned ob = sel ? bits : 0u;
        if constexpr ((p >> 1) == 0) w0 |= ob;
        else if constexpr ((p >> 1) == 1) w1 |= ob;
        else if constexpr ((p >> 1) == 2) w2 |= ob;
        else w3 |= ob;
    }
    uint4v u = {w0, w1, w2, w3};
    return __builtin_bit_cast(half8, u);
}

__device__ __forceinline__ half8 packx(unsigned a, unsigned b, unsigned c, unsigned d) {
    uint4v u = {a, b, c, d};
    return __builtin_bit_cast(half8, u);
}

struct Afrags {
    half8 A10, A11, A20, A21, A30, A31, A4, A5, A6, A7;
};

// one 32-row tile: build layer-1 B-frags from q regs, run 10-MFMA chain, store
__device__ __forceinline__ void tile_compute(const Afrags& A, float4 q0, float4 q1,
                                             float4 q2, float4 q3, int hb, int lane,
                                             int T, float* __restrict__ out, int nrows)
{
    const f32x16 z = {0.f,0.f,0.f,0.f, 0.f,0.f,0.f,0.f, 0.f,0.f,0.f,0.f, 0.f,0.f,0.f,0.f};
    half8 Bx0 = packx(ucast(cpk(q0.x, q0.y)), ucast(cpk(q0.z, q0.w)),
                      ucast(cpk(q1.x, q1.y)), ucast(cpk(q1.z, q1.w)));
    unsigned w2 = hb ? ucast(cpk(q3.z, q3.w))    // k28,29
                     : ucast(cpk(q3.x, q3.y));   // k20,21
    unsigned w3 = hb ? 0x00003C00u               // k30=1.0 (bias), k31=0
                     : ucast(cpk(q3.z, q3.w));   // k22,23
    half8 Bx1 = packx(ucast(cpk(q2.x, q2.y)), ucast(cpk(q2.z, q2.w)), w2, w3);

    f32x16 a1 = mfma_(A.A10, Bx0, z);
    a1 = mfma_(A.A11, Bx1, a1);
    f32x16 a2 = mfma_(A.A20, bfrag<0, -1>(a1, lane), z);
    a2 = mfma_(A.A21, bfrag<8, 8>(a1, lane), a2);
    f32x16 a3 = mfma_(A.A30, bfrag<0, -1>(a2, lane), z);
    a3 = mfma_(A.A31, bfrag<8, 3>(a2, lane), a3);
    f32x16 a4 = mfma_(A.A4, bfrag<0, 14>(a3, lane), z);
    f32x16 a5 = mfma_(A.A5, bfrag<0, 10>(a4, lane), z);
    f32x16 a6 = mfma_(A.A6, bfrag<0, 6>(a5, lane), z);
    f32x16 a7 = mfma_(A.A7, bfrag<0, 2>(a6, lane), z);

    const int row0 = T * 32;
    if (lane < 32) {
        int r = row0 + lane;
        if (r < nrows) out[r] = a7[0];
    }
}

__global__ __launch_bounds__(NTHREADS, 4) void mlp_mfma6(
    const float* __restrict__ x,
    const float* __restrict__ W1, const float* __restrict__ B1,
    const float* __restrict__ W2, const float* __restrict__ B2,
    const float* __restrict__ W3, const float* __restrict__ B3,
    const float* __restrict__ W4, const float* __restrict__ B4,
    const float* __restrict__ W5, const float* __restrict__ B5,
    const float* __restrict__ W6, const float* __restrict__ B6,
    const float* __restrict__ W7, const float* __restrict__ B7,
    float* __restrict__ out, int nrows)
{
    __shared__ __align__(16) __fp16 shw[5120];        // weights only, 10.2 KB

    const int t    = threadIdx.x;
    const int lane = t & 63;
    const int wid  = t >> 6;
    const int hb   = (lane >> 5) & 1;

    stageW<30, 24, 32>(W1, B1, shw + 0,    t);
    stageW<24, 19, 32>(W2, B2, shw + 1024, t);
    stageW<19, 14, 32>(W3, B3, shw + 2048, t);
    stageW<14, 10, 16>(W4, B4, shw + 3072, t);
    stageW<10, 6,  16>(W5, B5, shw + 3584, t);
    stageW<6,  2,  16>(W6, B6, shw + 4096, t);
    stageW<2,  1,  16>(W7, B7, shw + 4608, t);
    __syncthreads();                                  // the ONLY barrier

    Afrags A;
    A.A10 = ldA(shw + 0,    32, 0, lane); A.A11 = ldA(shw + 0,    32, 1, lane);
    A.A20 = ldA(shw + 1024, 32, 0, lane); A.A21 = ldA(shw + 1024, 32, 1, lane);
    A.A30 = ldA(shw + 2048, 32, 0, lane); A.A31 = ldA(shw + 2048, 32, 1, lane);
    A.A4  = ldA(shw + 3072, 16, 0, lane);
    A.A5  = ldA(shw + 3584, 16, 0, lane);
    A.A6  = ldA(shw + 4096, 16, 0, lane);
    A.A7  = ldA(shw + 4608, 16, 0, lane);

    const int tile0 = (blockIdx.x * 4 + wid) * TPW;
    const int myrow = lane & 31;
    const int off0  = hb * 8;
    const int off1  = 16 + hb * 8;
    const int off3  = 20 + hb * 6;       // 20..23 (lo) / 26..29 (hi, .z.w used)

    // ping-pong prefetch sets (depth 2)
    float4 qa0, qa1, qa2, qa3, qb0, qb1, qb2, qb3;
    {
        const float* b = x + ((size_t)(tile0 * 32 + myrow)) * 30;
        qa0 = ldg4(b + off0); qa1 = ldg4(b + off0 + 4);
        qa2 = ldg4(b + off1); qa3 = ldg4(b + off3);
        const float* c = b + 32 * 30;
        qb0 = ldg4(c + off0); qb1 = ldg4(c + off0 + 4);
        qb2 = ldg4(c + off1); qb3 = ldg4(c + off3);
    }

#pragma unroll
    for (int it = 0; it < TPW; it += 2) {
        // ---- phase A: consume set A, refill A with tile it+2 ----
        {
            float4 c0 = qa0, c1 = qa1, c2 = qa2, c3 = qa3;
            if (it + 2 < TPW) {
                const float* b = x + ((size_t)((tile0 + it + 2) * 32 + myrow)) * 30;
                qa0 = ldg4(b + off0); qa1 = ldg4(b + off0 + 4);
                qa2 = ldg4(b + off1); qa3 = ldg4(b + off3);
            }
            tile_compute(A, c0, c1, c2, c3, hb, lane, tile0 + it, out, nrows);
        }
        // ---- phase B: consume set B, refill B with tile it+3 ----
        {
            float4 c0 = qb0, c1 = qb1, c2 = qb2, c3 = qb3;
            if (it + 3 < TPW) {
                const float* b = x + ((size_t)((tile0 + it + 3) * 32 + myrow)) * 30;
                qb0 = ldg4(b + off0); qb1 = ldg4(b + off0 + 4);
                qb2 = ldg4(b + off1); qb3 = ldg4(b + off3);
            }
            tile_compute(A, c0, c1, c2, c3, hb, lane, tile0 + it + 1, out, nrows);
        }
    }
}

extern "C" void kernel_launch(void* const* d_in, const int* in_sizes, int n_in,
                              void* d_out, int out_size, void* d_ws, size_t ws_size,
                              hipStream_t stream) {
    const float* x = (const float*)d_in[0];
    int nrows = in_sizes[0] / 30;
    int rows_per_block = 4 * TPW * 32;                // 1024
    int blocks = (nrows + rows_per_block - 1) / rows_per_block;
    mlp_mfma6<<<blocks, NTHREADS, 0, stream>>>(
        x,
        (const float*)d_in[1],  (const float*)d_in[2],
        (const float*)d_in[3],  (const float*)d_in[4],
        (const float*)d_in[5],  (const float*)d_in[6],
        (const float*)d_in[7],  (const float*)d_in[8],
        (const float*)d_in[9],  (const float*)d_in[10],
        (const float*)d_in[11], (const float*)d_in[12],
        (const float*)d_in[13], (const float*)d_in[14],
        (float*)d_out, nrows);
}

// Round 26
// 29.785 us; speedup vs baseline: 1.0661x; 1.0661x over previous
//
#include <hip/hip_runtime.h>

// MLP 30->24->19->14->10->6->2->1 via MFMA (v_mfma_f32_32x32x16_f16).
// R25 vs R22-24 (31.3us, three neutral probes): REMOVE ALL CROSS-LANE OPS.
// The inter-layer bfrag needed 4x shfl_xor(32) (= ds_bpermute, ~40cyc DS
// latency inside the serial MFMA chain). Fix: permute the K-AXIS of each
// next layer's A operand at staging time to match D's native row layout:
//   A'[m][16b + c] = W[m][16b + phi(c)],  phi(c)=(c&3)+8*((c>>2)&1)+4*(c>>3)
// (involution). Then the B-fragment is a straight cvt_pkrtz of the lane's
// own 8 D-regs: ZERO shuffles, pure VALU. Bias 1.0 injected at the D-reg
// slot of row FIN (per-layer constants derived from row=(i&3)+8(i>>2)+4hb).
// Layer 1 keeps identity staging (x-frags built in natural k order).
// Everything else = R22/R23 proven structure: per-lane direct x loads
// (4x float4), 1-tile prefetch, A-frags hoisted, TPW=8, (256,4), 1 barrier.

#define NTHREADS 256
#define TPW 8

typedef __fp16       h2     __attribute__((ext_vector_type(2)));
typedef __fp16       half8  __attribute__((ext_vector_type(8)));
typedef float        f32x16 __attribute__((ext_vector_type(16)));
typedef unsigned int uint4v __attribute__((ext_vector_type(4)));

__device__ __forceinline__ h2 cpk(float a, float b) {
    return __builtin_bit_cast(h2, __builtin_amdgcn_cvt_pkrtz(a, b));
}
__device__ __forceinline__ h2 relu2(h2 v) {
    h2 z = {(__fp16)0.f, (__fp16)0.f};
#if __has_builtin(__builtin_elementwise_max)
    return __builtin_elementwise_max(v, z);
#else
    v.x = v.x > (__fp16)0.f ? v.x : (__fp16)0.f;
    v.y = v.y > (__fp16)0.f ? v.y : (__fp16)0.f;
    return v;
#endif
}
__device__ __forceinline__ unsigned ucast(h2 v) { return __builtin_bit_cast(unsigned, v); }

__device__ __forceinline__ f32x16 mfma_(half8 A, half8 B, f32x16 C) {
    return __builtin_amdgcn_mfma_f32_32x32x16_f16(A, B, C, 0, 0, 0);
}

__device__ __forceinline__ float4 ldg4(const float* p) {
    float4 v;
    __builtin_memcpy(&v, p, 16);
    return v;
}

// ---- weight staging. PERM: source feature f = 16b + phi(c) so that the
// next layer's B-frag needs no cross-lane swap. Bias at feature FIN. ----
template <int FIN, int FOUT, int KPAD, bool PERM>
__device__ __forceinline__ void stageW(const float* __restrict__ W, const float* __restrict__ B,
                                       __fp16* __restrict__ sbase, int t) {
    for (int idx = t; idx < 32 * KPAD; idx += NTHREADS) {
        int m = idx / KPAD;
        int k = idx & (KPAD - 1);
        int f;
        if (PERM) {
            int c = k & 15;
            f = (k & ~15) + ((c & 3) + 8 * ((c >> 2) & 1) + 4 * ((c >> 3) & 1));
        } else {
            f = k;
        }
        float v = 0.f;
        if (m < FOUT) {
            if (f < FIN) v = W[m * FIN + f];
            else if (f == FIN) v = B[m];
        }
        int byte = idx * 2;
        byte ^= (m & 7) << 4;
        *(__fp16*)((char*)sbase + byte) = (__fp16)v;
    }
}

// A-fragment read: lane holds A'[m=lane&31][k = ks*16 + 8*(lane>>5) + j]
__device__ __forceinline__ half8 ldA(const __fp16* base, int KPAD, int ks, int lane) {
    int m = lane & 31;
    int byte = (m * KPAD + ks * 16 + ((lane >> 5) & 1) * 8) * 2;
    byte ^= (m & 7) << 4;
    return __builtin_bit_cast(half8, *(const uint4v*)((const char*)base + byte));
}

// B-fragment, NO shuffles: straight cvt of lane's own D-regs R..R+7.
// BW = word for bias 1.0 (-1 none), BODD = element, BHB = which lane half.
template <int R, int BW, int BODD, int BHB>
__device__ __forceinline__ half8 bfragn(const f32x16& d, int hb) {
    unsigned w0 = ucast(relu2(cpk(d[R + 0], d[R + 1])));
    unsigned w1 = ucast(relu2(cpk(d[R + 2], d[R + 3])));
    unsigned w2 = ucast(relu2(cpk(d[R + 4], d[R + 5])));
    unsigned w3 = ucast(relu2(cpk(d[R + 6], d[R + 7])));
    if constexpr (BW >= 0) {
        constexpr unsigned bits = BODD ? 0x3C000000u : 0x00003C00u;  // f16 1.0
        unsigned ob = (hb == BHB) ? bits : 0u;
        if constexpr (BW == 0) w0 |= ob;
        else if constexpr (BW == 1) w1 |= ob;
        else if constexpr (BW == 2) w2 |= ob;
        else w3 |= ob;
    }
    uint4v u = {w0, w1, w2, w3};
    return __builtin_bit_cast(half8, u);
}

__device__ __forceinline__ half8 packx(unsigned a, unsigned b, unsigned c, unsigned d) {
    uint4v u = {a, b, c, d};
    return __builtin_bit_cast(half8, u);
}

__global__ __launch_bounds__(NTHREADS, 4) void mlp_mfma7(
    const float* __restrict__ x,
    const float* __restrict__ W1, const float* __restrict__ B1,
    const float* __restrict__ W2, const float* __restrict__ B2,
    const float* __restrict__ W3, const float* __restrict__ B3,
    const float* __restrict__ W4, const float* __restrict__ B4,
    const float* __restrict__ W5, const float* __restrict__ B5,
    const float* __restrict__ W6, const float* __restrict__ B6,
    const float* __restrict__ W7, const float* __restrict__ B7,
    float* __restrict__ out, int nrows)
{
    __shared__ __align__(16) __fp16 shw[5120];        // weights only, 10.2 KB

    const int t    = threadIdx.x;
    const int lane = t & 63;
    const int wid  = t >> 6;
    const int hb   = (lane >> 5) & 1;

    stageW<30, 24, 32, false>(W1, B1, shw + 0,    t);  // L1: identity (x natural)
    stageW<24, 19, 32, true >(W2, B2, shw + 1024, t);
    stageW<19, 14, 32, true >(W3, B3, shw + 2048, t);
    stageW<14, 10, 16, true >(W4, B4, shw + 3072, t);
    stageW<10, 6,  16, true >(W5, B5, shw + 3584, t);
    stageW<6,  2,  16, true >(W6, B6, shw + 4096, t);
    stageW<2,  1,  16, true >(W7, B7, shw + 4608, t);
    __syncthreads();                                  // the ONLY barrier

    // ---- hoist all A-fragments into registers (10 x 4 VGPR) ----
    const half8 A10 = ldA(shw + 0,    32, 0, lane), A11 = ldA(shw + 0,    32, 1, lane);
    const half8 A20 = ldA(shw + 1024, 32, 0, lane), A21 = ldA(shw + 1024, 32, 1, lane);
    const half8 A30 = ldA(shw + 2048, 32, 0, lane), A31 = ldA(shw + 2048, 32, 1, lane);
    const half8 A4  = ldA(shw + 3072, 16, 0, lane);
    const half8 A5  = ldA(shw + 3584, 16, 0, lane);
    const half8 A6  = ldA(shw + 4096, 16, 0, lane);
    const half8 A7  = ldA(shw + 4608, 16, 0, lane);

    const f32x16 z = {0.f,0.f,0.f,0.f, 0.f,0.f,0.f,0.f, 0.f,0.f,0.f,0.f, 0.f,0.f,0.f,0.f};

    const int tile0 = (blockIdx.x * 4 + wid) * TPW;
    const int myrow = lane & 31;
    const int off0  = hb * 8;
    const int off1  = 16 + hb * 8;
    const int off3  = 20 + hb * 6;       // 20..23 (lo) / 26..29 (hi, .z.w used)

    float4 q0, q1, q2, q3;
    {
        const float* b = x + ((size_t)(tile0 * 32 + myrow)) * 30;
        q0 = ldg4(b + off0);
        q1 = ldg4(b + off0 + 4);
        q2 = ldg4(b + off1);
        q3 = ldg4(b + off3);
    }

    for (int it = 0; it < TPW; ++it) {
        const int T = tile0 + it;

        // ---- layer-1 B-frags from prefetch regs (natural k order) ----
        half8 Bx0 = packx(ucast(cpk(q0.x, q0.y)), ucast(cpk(q0.z, q0.w)),
                          ucast(cpk(q1.x, q1.y)), ucast(cpk(q1.z, q1.w)));
        unsigned w2 = hb ? ucast(cpk(q3.z, q3.w))    // k28,29
                         : ucast(cpk(q3.x, q3.y));   // k20,21
        unsigned w3 = hb ? 0x00003C00u               // k30=1.0 (bias), k31=0
                         : ucast(cpk(q3.z, q3.w));   // k22,23
        half8 Bx1 = packx(ucast(cpk(q2.x, q2.y)), ucast(cpk(q2.z, q2.w)), w2, w3);

        // ---- issue next tile's loads (hide under MFMA chain) ----
        if (it + 1 < TPW) {
            const float* b = x + ((size_t)((T + 1) * 32 + myrow)) * 30;
            q0 = ldg4(b + off0);
            q1 = ldg4(b + off0 + 4);
            q2 = ldg4(b + off1);
            q3 = ldg4(b + off3);
        }

        // ---- 10-MFMA chain, shuffle-free transitions ----
        f32x16 a1 = mfma_(A10, Bx0, z);
        a1 = mfma_(A11, Bx1, a1);
        // L2: bias feat 24 -> reg12 -> block1 word2, even, lo
        f32x16 a2 = mfma_(A20, bfragn<0, -1, 0, 0>(a1, hb), z);
        a2 = mfma_(A21, bfragn<8, 2, 0, 0>(a1, hb), a2);
        // L3: bias feat 19 -> reg11 -> block1 word1, odd, lo
        f32x16 a3 = mfma_(A30, bfragn<0, -1, 0, 0>(a2, hb), z);
        a3 = mfma_(A31, bfragn<8, 1, 1, 0>(a2, hb), a3);
        // L4: bias feat 14 -> reg6, hi -> word3, even, hi
        f32x16 a4 = mfma_(A4, bfragn<0, 3, 0, 1>(a3, hb), z);
        // L5: bias feat 10 -> reg6, lo -> word3, even, lo
        f32x16 a5 = mfma_(A5, bfragn<0, 3, 0, 0>(a4, hb), z);
        // L6: bias feat 6 -> reg2, hi -> word1, even, hi
        f32x16 a6 = mfma_(A6, bfragn<0, 1, 0, 1>(a5, hb), z);
        // L7: bias feat 2 -> reg2, lo -> word1, even, lo
        f32x16 a7 = mfma_(A7, bfragn<0, 1, 0, 0>(a6, hb), z);

        const int row0 = T * 32;
        if (lane < 32) {
            int r = row0 + lane;
            if (r < nrows) out[r] = a7[0];
        }
    }
}

extern "C" void kernel_launch(void* const* d_in, const int* in_sizes, int n_in,
                              void* d_out, int out_size, void* d_ws, size_t ws_size,
                              hipStream_t stream) {
    const float* x = (const float*)d_in[0];
    int nrows = in_sizes[0] / 30;
    int rows_per_block = 4 * TPW * 32;                // 1024
    int blocks = (nrows + rows_per_block - 1) / rows_per_block;
    mlp_mfma7<<<blocks, NTHREADS, 0, stream>>>(
        x,
        (const float*)d_in[1],  (const float*)d_in[2],
        (const float*)d_in[3],  (const float*)d_in[4],
        (const float*)d_in[5],  (const float*)d_in[6],
        (const float*)d_in[7],  (const float*)d_in[8],
        (const float*)d_in[9],  (const float*)d_in[10],
        (const float*)d_in[11], (const float*)d_in[12],
        (const float*)d_in[13], (const float*)d_in[14],
        (float*)d_out, nrows);
}